// Round 8
// baseline (186.172 us; speedup 1.0000x reference)
//
#include <hip/hip_runtime.h>
#include <math.h>

// CoralLossV2: mean over (B, Km1) of
//   max(x,0) - x*[t > k] + log1p(exp(-|x|))  ==  softplus(x) - x*[t > k]
// B = 524288, Km1 = 64, logits fp32, targets int32, output: 1 fp32 scalar.
//
// R7 post-mortem: nt loads cut kernel ~70 -> ~56 us, confirming the
// dirty-L3 theory: the harness's 537 MB poison fill leaves L3 full of dirty
// lines; every read that ALLOCATES in L3 forces a dirty-victim writeback
// (~2x HBM traffic: 134 read + ~134 drain ~= 39 us + slack = 56 us).
// __builtin_nontemporal_load only sets NT (L2 policy). On gfx940+ the
// L3/MALL no-allocate policy is NT+SC1. R8: logits via
// llvm.amdgcn.raw.buffer.load.v4f32 with aux = NT|SC1 = 18
// -> buffer_load_dwordx4 nt sc1 (probe, never allocate). Targets revert to
// plain cached loads (L1/L2 reuse: each 64B line read by 4 waves).

#define BLOCK 256
#define GRID 2048
#define STRIDE (GRID * BLOCK)

typedef int v4i __attribute__((ext_vector_type(4)));
typedef float v4f __attribute__((ext_vector_type(4)));

// LLVM intrinsic alias (composable_kernel-style): compiler tracks vmcnt for us.
extern "C" __device__ v4f
__llvm_amdgcn_raw_buffer_load_v4f32(v4i rsrc, int voffset, int soffset, int aux)
    __asm("llvm.amdgcn.raw.buffer.load.v4f32");

#define AUX_NT_SC1 18   // CPol: SLC/NT=2 | SCC/SC1=16

__device__ __forceinline__ v4i make_srd(const void* p) {
    union { const void* ptr; unsigned u[2]; } a;
    a.ptr = p;
    v4i r;
    r.x = (int)a.u[0];
    r.y = (int)(a.u[1] & 0xFFFF);  // stride = 0
    r.z = (int)0xFFFFFFFF;         // num_records: bounds check disabled
    r.w = 0x00020000;              // raw untyped dword access
    return r;
}

__device__ __forceinline__ float bce4(const v4f x4, const int c) {
    const float LOG2E = 1.44269504088896f;
    const float LN2   = 0.69314718055995f;
    float s = 0.0f;
    #pragma unroll
    for (int j = 0; j < 4; ++j) {
        const float x = x4[j];
        // log1p(exp(-|x|)) = ln2 * log2(1 + exp2(-|x|*log2e)) via hw trans ops
        const float e  = __builtin_amdgcn_exp2f(-fabsf(x) * LOG2E);
        const float lg = __builtin_amdgcn_logf(1.0f + e);
        // max(x,0) - x*[c > j] == (c > j) ? max(-x,0) : max(x,0)
        const float m  = fmaxf((c > j) ? -x : x, 0.0f);
        s += fmaf(LN2, lg, m);
    }
    return s;
}

__device__ __forceinline__ float block_reduce(float acc, float* wave_sums) {
    #pragma unroll
    for (int off = 32; off > 0; off >>= 1)
        acc += __shfl_down(acc, off, 64);
    const int lane = threadIdx.x & 63;
    const int wid = threadIdx.x >> 6;
    if (lane == 0) wave_sums[wid] = acc;
    __syncthreads();
    float s = 0.0f;
    if (threadIdx.x == 0) {
        #pragma unroll
        for (int w = 0; w < BLOCK / 64; ++w) s += wave_sums[w];
    }
    return s;
}

__global__ __launch_bounds__(BLOCK) void coral_loss_main(
    const float* __restrict__ logits,
    const int* __restrict__ targets,
    float* __restrict__ partials,   // GRID floats in d_ws
    int n_vec4,                     // B*Km1/4
    float inv_count)                // 1/(B*Km1)
{
    const v4i srd = make_srd(logits);
    float a0 = 0.0f, a1 = 0.0f, a2 = 0.0f, a3 = 0.0f;
    int idx = blockIdx.x * BLOCK + threadIdx.x;

    for (; idx + 3 * STRIDE < n_vec4; idx += 4 * STRIDE) {
        const int i0 = idx, i1 = idx + STRIDE, i2 = idx + 2 * STRIDE, i3 = idx + 3 * STRIDE;
        // logits: streaming loads, no allocation at any cache level (nt sc1)
        const v4f x0 = __llvm_amdgcn_raw_buffer_load_v4f32(srd, i0 * 16, 0, AUX_NT_SC1);
        const v4f x1 = __llvm_amdgcn_raw_buffer_load_v4f32(srd, i1 * 16, 0, AUX_NT_SC1);
        const v4f x2 = __llvm_amdgcn_raw_buffer_load_v4f32(srd, i2 * 16, 0, AUX_NT_SC1);
        const v4f x3 = __llvm_amdgcn_raw_buffer_load_v4f32(srd, i3 * 16, 0, AUX_NT_SC1);
        // targets: cached (each 64B line is re-read by 4 waves)
        const int c0 = targets[i0 >> 4] - ((i0 & 15) << 2);
        const int c1 = targets[i1 >> 4] - ((i1 & 15) << 2);
        const int c2 = targets[i2 >> 4] - ((i2 & 15) << 2);
        const int c3 = targets[i3 >> 4] - ((i3 & 15) << 2);
        a0 += bce4(x0, c0);
        a1 += bce4(x1, c1);
        a2 += bce4(x2, c2);
        a3 += bce4(x3, c3);
    }
    for (; idx < n_vec4; idx += STRIDE) {
        const v4f x = __llvm_amdgcn_raw_buffer_load_v4f32(srd, idx * 16, 0, AUX_NT_SC1);
        a0 += bce4(x, targets[idx >> 4] - ((idx & 15) << 2));
    }

    float acc = ((a0 + a1) + (a2 + a3)) * inv_count;

    __shared__ float wave_sums[BLOCK / 64];
    const float s = block_reduce(acc, wave_sums);
    if (threadIdx.x == 0) partials[blockIdx.x] = s;   // plain store, no atomic
}

__global__ __launch_bounds__(BLOCK) void coral_loss_finish(
    const float* __restrict__ partials,
    float* __restrict__ out,
    int n_partials)
{
    float acc = 0.0f;
    for (int i = threadIdx.x; i < n_partials; i += BLOCK)
        acc += partials[i];
    __shared__ float wave_sums[BLOCK / 64];
    const float s = block_reduce(acc, wave_sums);
    if (threadIdx.x == 0) out[0] = s;
}

extern "C" void kernel_launch(void* const* d_in, const int* in_sizes, int n_in,
                              void* d_out, int out_size, void* d_ws, size_t ws_size,
                              hipStream_t stream) {
    const float* logits = (const float*)d_in[0];
    const int* targets = (const int*)d_in[1];
    float* out = (float*)d_out;
    float* partials = (float*)d_ws;

    const int n_logits = in_sizes[0];       // B * Km1
    const int n_vec4 = n_logits / 4;
    const float inv_count = 1.0f / (float)n_logits;

    coral_loss_main<<<GRID, BLOCK, 0, stream>>>(
        logits, targets, partials, n_vec4, inv_count);
    coral_loss_finish<<<1, BLOCK, 0, stream>>>(partials, out, GRID);
}

// Round 9
// 183.369 us; speedup vs baseline: 1.0153x; 1.0153x over previous
//
#include <hip/hip_runtime.h>
#include <math.h>

// CoralLossV2: mean over (B, Km1) of
//   max(x,0) - x*[t > k] + log1p(exp(-|x|))  ==  softplus(x) - x*[t > k]
// B = 524288, Km1 = 64, logits fp32, targets int32, output: 1 fp32 scalar.
//
// R8 post-mortem: buffer-load NT|SC1 regressed (186.2 vs R7's 182.6).
// The harness restores inputs AFTER the poison fill, so ~half the logits
// are dirty L3 lines at kernel start (R1: FETCH=68MB ~= half input).
// Plain nt probes-and-hits those lines; SC1 penalizes the hit path.
// Structural floor: ~68 MB compulsory reads + ~256 MB residual dirty-L3
// drain ~= 390 MB / 6.9 TB/s ~= 56 us == R7's backed-out kernel time.
// R9: revert to the exact R7 configuration (best measured).

#define BLOCK 256
#define GRID 2048
#define STRIDE (GRID * BLOCK)

typedef float floatx4 __attribute__((ext_vector_type(4)));

__device__ __forceinline__ float bce4(const floatx4 x4, const int c) {
    const float LOG2E = 1.44269504088896f;
    const float LN2   = 0.69314718055995f;
    float s = 0.0f;
    #pragma unroll
    for (int j = 0; j < 4; ++j) {
        const float x = x4[j];
        // log1p(exp(-|x|)) = ln2 * log2(1 + exp2(-|x|*log2e)) via hw trans ops
        const float e  = __builtin_amdgcn_exp2f(-fabsf(x) * LOG2E);
        const float lg = __builtin_amdgcn_logf(1.0f + e);
        // max(x,0) - x*[c > j] == (c > j) ? max(-x,0) : max(x,0)
        const float m  = fmaxf((c > j) ? -x : x, 0.0f);
        s += fmaf(LN2, lg, m);
    }
    return s;
}

__device__ __forceinline__ float block_reduce(float acc, float* wave_sums) {
    #pragma unroll
    for (int off = 32; off > 0; off >>= 1)
        acc += __shfl_down(acc, off, 64);
    const int lane = threadIdx.x & 63;
    const int wid = threadIdx.x >> 6;
    if (lane == 0) wave_sums[wid] = acc;
    __syncthreads();
    float s = 0.0f;
    if (threadIdx.x == 0) {
        #pragma unroll
        for (int w = 0; w < BLOCK / 64; ++w) s += wave_sums[w];
    }
    return s;
}

__global__ __launch_bounds__(BLOCK) void coral_loss_main(
    const float* __restrict__ logits,
    const int* __restrict__ targets,
    float* __restrict__ partials,   // GRID floats in d_ws
    int n_vec4,                     // B*Km1/4
    float inv_count)                // 1/(B*Km1)
{
    const floatx4* __restrict__ L4 = reinterpret_cast<const floatx4*>(logits);
    float a0 = 0.0f, a1 = 0.0f, a2 = 0.0f, a3 = 0.0f;
    int idx = blockIdx.x * BLOCK + threadIdx.x;

    for (; idx + 3 * STRIDE < n_vec4; idx += 4 * STRIDE) {
        const int i0 = idx, i1 = idx + STRIDE, i2 = idx + 2 * STRIDE, i3 = idx + 3 * STRIDE;
        const floatx4 x0 = __builtin_nontemporal_load(&L4[i0]);
        const floatx4 x1 = __builtin_nontemporal_load(&L4[i1]);
        const floatx4 x2 = __builtin_nontemporal_load(&L4[i2]);
        const floatx4 x3 = __builtin_nontemporal_load(&L4[i3]);
        const int c0 = __builtin_nontemporal_load(&targets[i0 >> 4]) - ((i0 & 15) << 2);
        const int c1 = __builtin_nontemporal_load(&targets[i1 >> 4]) - ((i1 & 15) << 2);
        const int c2 = __builtin_nontemporal_load(&targets[i2 >> 4]) - ((i2 & 15) << 2);
        const int c3 = __builtin_nontemporal_load(&targets[i3 >> 4]) - ((i3 & 15) << 2);
        a0 += bce4(x0, c0);
        a1 += bce4(x1, c1);
        a2 += bce4(x2, c2);
        a3 += bce4(x3, c3);
    }
    for (; idx < n_vec4; idx += STRIDE) {
        a0 += bce4(__builtin_nontemporal_load(&L4[idx]),
                   __builtin_nontemporal_load(&targets[idx >> 4]) - ((idx & 15) << 2));
    }

    float acc = ((a0 + a1) + (a2 + a3)) * inv_count;

    __shared__ float wave_sums[BLOCK / 64];
    const float s = block_reduce(acc, wave_sums);
    if (threadIdx.x == 0) partials[blockIdx.x] = s;   // plain store, no atomic
}

__global__ __launch_bounds__(BLOCK) void coral_loss_finish(
    const float* __restrict__ partials,
    float* __restrict__ out,
    int n_partials)
{
    float acc = 0.0f;
    for (int i = threadIdx.x; i < n_partials; i += BLOCK)
        acc += partials[i];
    __shared__ float wave_sums[BLOCK / 64];
    const float s = block_reduce(acc, wave_sums);
    if (threadIdx.x == 0) out[0] = s;
}

extern "C" void kernel_launch(void* const* d_in, const int* in_sizes, int n_in,
                              void* d_out, int out_size, void* d_ws, size_t ws_size,
                              hipStream_t stream) {
    const float* logits = (const float*)d_in[0];
    const int* targets = (const int*)d_in[1];
    float* out = (float*)d_out;
    float* partials = (float*)d_ws;

    const int n_logits = in_sizes[0];       // B * Km1
    const int n_vec4 = n_logits / 4;
    const float inv_count = 1.0f / (float)n_logits;

    coral_loss_main<<<GRID, BLOCK, 0, stream>>>(
        logits, targets, partials, n_vec4, inv_count);
    coral_loss_finish<<<1, BLOCK, 0, stream>>>(partials, out, GRID);
}